// Round 9
// baseline (89.373 us; speedup 1.0000x reference)
//
#include <hip/hip_runtime.h>
#include <math.h>

#define B_   8
#define L_   4096
#define D_   768
#define NC_  4096
#define NCH_ 2048
#define M_   (B_*NC_)    // 32768 (b,c) pairs
#define MC_  (B_*NCH_)   // 16384 active compact rows
#define NKT_ 24          // K-tiles of 32 (K=768)
#define META_BLOCKS 128
#define WPREP_BLOCKS 144
#define GEMM_BLOCKS 256  // 256 mtiles (BM=64) x 1 ntile (BN=768), 1/CU

typedef __attribute__((ext_vector_type(8))) short short8;
typedef __attribute__((ext_vector_type(4))) float f32x4;
typedef unsigned int u32;
typedef unsigned short u16;

__device__ __forceinline__ void gload16(const void* g, void* l) {
    __builtin_amdgcn_global_load_lds((const __attribute__((address_space(1))) u32*)g,
                                     (__attribute__((address_space(3))) u32*)l, 16, 0, 0);
}

__device__ __forceinline__ u16 f2bf(float f) {           // RNE bf16
    union { float f; u32 u; } v; v.f = f;
    u32 r = v.u + 0x7fffu + ((v.u >> 16) & 1u);
    return (u16)(r >> 16);
}

// tanh(x) = 1 - 2/(e^{2x}+1). Saturates to +-1.
__device__ __forceinline__ float tanh_fast(float x) {
    float e = __builtin_amdgcn_exp2f(x * 2.885390081777927f);
    return 1.f - 2.f * __builtin_amdgcn_rcpf(e + 1.f);
}

__device__ __forceinline__ int lower_bound(const int* __restrict__ a, int lo, int hi, int v) {
    while (lo < hi) {
        int mid = (lo + hi) >> 1;
        if (a[mid] < v) lo = mid + 1; else hi = mid;
    }
    return lo;
}

// -------- kernel 1: prep = meta+keep (+wprep role blocks) --------
// meta: one thread per (b,c), idx = c*8+b. e-boundary via neighbor shuffle.
__global__ void prep_kernel(const int* __restrict__ seg,
                            const int* __restrict__ padm,
                            const int* __restrict__ regm,
                            const int* __restrict__ spm,
                            const float* __restrict__ Wm,
                            u16* __restrict__ wt,
                            int* __restrict__ stA, int* __restrict__ cntA,
                            int* __restrict__ act,
                            float* __restrict__ out_mp, float* __restrict__ out_mr,
                            float* __restrict__ out_sp,
                            float2* __restrict__ partials) {
    __shared__ float shm[64 * 65 + 8];
    int blk = blockIdx.x;
    int t = threadIdx.x;
    if (blk >= META_BLOCKS) {                    // ---- wprep role ----
        int wb = blk - META_BLOCKS;
        int bk = wb % 12, bn = wb / 12;
        int k0 = bk * 64, n0 = bn * 64;
        int ln = t & 63, lw = t >> 6;
        #pragma unroll
        for (int p = 0; p < 16; ++p) {
            int kl = lw + p * 4;
            shm[kl * 65 + ln] = Wm[(size_t)(k0 + kl) * D_ + n0 + ln];  // coalesced over n
        }
        __syncthreads();
        #pragma unroll
        for (int p = 0; p < 16; ++p) {
            int nl = lw + p * 4;
            wt[(size_t)(n0 + nl) * D_ + k0 + ln] = f2bf(shm[ln * 65 + nl]);
        }
        return;
    }
    // ---- meta role ----
    int idx = blk * 256 + t;                     // [0, M_)
    int c = idx >> 3, b = idx & 7;
    const int* row = seg + b * L_;
    int s = lower_bound(row, 0, L_, c);
    int e = __shfl_down(s, 8);                   // lane+8 holds (c+1, b)
    if ((t & 63) >= 56) e = lower_bound(row, s, L_, c + 1);
    int cnt = e - s;
    int mp = 0, mr = 0;
    if (cnt > 0) { mp = padm[b * L_ + s]; mr = regm[b * L_ + s]; }
    int sp = (mp == 0) ? -1 : spm[b * L_ + s];
    int k = mp;                                  // keep = OR of mp over the 8 b's
    k |= __shfl_xor(k, 1);
    k |= __shfl_xor(k, 2);
    k |= __shfl_xor(k, 4);
    k = k ? 1 : 0;
    out_mp[b * NC_ + c] = (float)mp;             // mp*keep == mp
    out_mr[b * NC_ + c] = (float)(k ? mr : 0);
    out_sp[b * NC_ + c] = (float)(k ? sp : 0);
    if (c < NCH_) {
        int mc = b * NCH_ + c;
        stA[mc] = s;
        cntA[mc] = cnt;
        act[mc] = (k && cnt > 0) ? 1 : 0;
    }
    float numP = (float)(k * mr);
    float denP = (float)(cnt * mr);
    #pragma unroll
    for (int off = 32; off; off >>= 1) {
        numP += __shfl_down(numP, off);
        denP += __shfl_down(denP, off);
    }
    __syncthreads();
    if ((t & 63) == 0) { shm[(t >> 6) * 2] = numP; shm[(t >> 6) * 2 + 1] = denP; }
    __syncthreads();
    if (t == 0)
        partials[blk] = make_float2(shm[0] + shm[2] + shm[4] + shm[6],
                                    shm[1] + shm[3] + shm[5] + shm[7]);
}

// -------- kernel 2: fused mean+GEMM+zero (+rate block) --------
// Block = 64 rows x 768 cols. Waves 0-5: GEMM consumers (128 cols each).
// Waves 6-7: mean producers -> A slice (64x32 bf16) in LDS ring-2.
// B: ring-3 48KB tiles via global_load_lds, counted vmcnt(8).
// Epilogue: consumers write real rows; all threads zero 196.6KB dead share.
__global__ __launch_bounds__(512, 1) void fused_kernel(
        const float* __restrict__ x,
        const int* __restrict__ stA, const int* __restrict__ cntA,
        const u16* __restrict__ wt,               // [768][768] transposed bf16
        const float* __restrict__ bias,
        const int* __restrict__ act,
        const float2* __restrict__ partials,
        float* __restrict__ out, float* __restrict__ rateOut) {
    __shared__ char sB[3 * 49152];                // 144 KB B ring
    __shared__ char sA[2 * 4096];                 // 8 KB A slice ring
    __shared__ int sMeta[128];                    // st[64], cnt[64]
    __shared__ float rb[4];
    int bid = blockIdx.x;
    int t = threadIdx.x;
    if (bid >= GEMM_BLOCKS) {                     // ---- rate role ----
        float n = 0.f, d = 0.f;
        if (t < META_BLOCKS) { float2 p = partials[t]; n = p.x; d = p.y; }
        #pragma unroll
        for (int off = 32; off; off >>= 1) { n += __shfl_down(n, off); d += __shfl_down(d, off); }
        if (t < META_BLOCKS && (t & 63) == 0) { rb[(t >> 6) * 2] = n; rb[(t >> 6) * 2 + 1] = d; }
        __syncthreads();
        if (t == 0) rateOut[0] = (rb[0] + rb[2]) / (rb[1] + rb[3]);
        return;
    }
    int wg = (bid & 7) * 32 + (bid >> 3);         // XCD-chunked
    int m0 = wg << 6;                             // 64 active rows, same b
    int b = m0 >> 11;
    int lane = t & 63, w = t >> 6;

    if (t < 64) { sMeta[t] = stA[m0 + t]; sMeta[64 + t] = cntA[m0 + t]; }

    const char* bT = (const char*)wt;             // 768 rows x 1536 B
    const float* xb = x + (size_t)b * L_ * D_;

    // B staging src (consumer threads t<384): sweep j covers i = t + j*384
    int srcB[8];
    #pragma unroll
    for (int j = 0; j < 8; ++j) {
        int i = t + j * 384;
        int r = i >> 2, s = i & 3;
        srcB[j] = r * 1536 + ((s ^ ((r ^ (r >> 2)) & 3)) << 4);
    }
    int dbB = w * 1024;

    // fragment read offsets (swizzled, loop-invariant)
    int aoff[4], boff[8];
    #pragma unroll
    for (int f = 0; f < 4; ++f) {
        int r = f * 16 + (lane & 15);
        aoff[f] = r * 64 + ((((lane >> 4)) ^ ((r ^ (r >> 2)) & 3)) << 4);
    }
    #pragma unroll
    for (int g = 0; g < 8; ++g) {
        int r = w * 128 + g * 16 + (lane & 15);
        boff[g] = r * 64 + ((((lane >> 4)) ^ ((r ^ (r >> 2)) & 3)) << 4);
    }

    // prologue: consumers stage B tiles 0,1
    if (w < 6) {
        #pragma unroll
        for (int p = 0; p < 2; ++p)
            #pragma unroll
            for (int j = 0; j < 8; ++j)
                gload16(bT + srcB[j] + (p << 6), sB + p * 49152 + j * 6144 + dbB);
    }
    __syncthreads();   // sMeta visible; per-wave vmcnt drain (B t0,t1 landed)

    // producer helper: mean slice for K-tile kt -> sA slot (kt&1)
    auto produceA = [&](int kt) {
        int pt = t - 384;
        int r = pt >> 1, h = pt & 1;
        int st = sMeta[r], cnt = sMeta[64 + r];
        const float* base = xb + (size_t)st * D_ + (kt << 5) + h * 16;
        float a16[16];
        #pragma unroll
        for (int i = 0; i < 16; ++i) a16[i] = 0.f;
        int tk = 0;
        for (; tk + 2 <= cnt; tk += 2) {          // 2-token unroll: 8 float4 in flight
            const float* p0 = base + (size_t)tk * D_;
            const float* p1 = p0 + D_;
            #pragma unroll
            for (int i = 0; i < 16; ++i) a16[i] += p0[i] + p1[i];
        }
        if (tk < cnt) {
            const float* p0 = base + (size_t)tk * D_;
            #pragma unroll
            for (int i = 0; i < 16; ++i) a16[i] += p0[i];
        }
        float inv = (cnt > 0) ? 1.f / (float)cnt : 0.f;
        short8 v1, v2;
        #pragma unroll
        for (int i = 0; i < 8; ++i) v1[i] = (short)f2bf(a16[i] * inv);
        #pragma unroll
        for (int i = 0; i < 8; ++i) v2[i] = (short)f2bf(a16[8 + i] * inv);
        char* slice = sA + ((kt & 1) << 12);
        int sw = (r ^ (r >> 2)) & 3;
        *(short8*)(slice + r * 64 + (((2 * h) ^ sw) << 4)) = v1;
        *(short8*)(slice + r * 64 + (((2 * h + 1) ^ sw) << 4)) = v2;
    };

    f32x4 acc[4][8] = {};

    if (w >= 6) produceA(0);                      // A tile 0 into slot 0

    #pragma unroll 1
    for (int kt = 0; kt < NKT_; ++kt) {
        if (w < 6) {
            if (kt < NKT_ - 1) asm volatile("s_waitcnt vmcnt(8)" ::: "memory");
            else               asm volatile("s_waitcnt vmcnt(0)" ::: "memory");
        } else {
            asm volatile("s_waitcnt lgkmcnt(0)" ::: "memory");   // A writes done
        }
        __builtin_amdgcn_s_barrier();
        __builtin_amdgcn_sched_barrier(0);
        if (w < 6) {
            const char* curA = sA + ((kt & 1) << 12);
            const char* curB = sB + (kt % 3) * 49152;
            short8 afr[4], bfr[8];
            #pragma unroll
            for (int f = 0; f < 4; ++f) afr[f] = *(const short8*)(curA + aoff[f]);
            #pragma unroll
            for (int g = 0; g < 8; ++g) bfr[g] = *(const short8*)(curB + boff[g]);
            if (kt + 2 < NKT_) {                  // stage B tile kt+2 (slot read at kt-1)
                int kof = (kt + 2) << 6;
                char* d = sB + ((kt + 2) % 3) * 49152;
                #pragma unroll
                for (int j = 0; j < 8; ++j)
                    gload16(bT + srcB[j] + kof, d + j * 6144 + dbB);
            }
            __builtin_amdgcn_s_setprio(1);
            #pragma unroll
            for (int f = 0; f < 4; ++f)
                #pragma unroll
                for (int g = 0; g < 8; ++g)
                    acc[f][g] = __builtin_amdgcn_mfma_f32_16x16x32_bf16(
                        afr[f], bfr[g], acc[f][g], 0, 0, 0);
            __builtin_amdgcn_s_setprio(0);
        } else {
            if (kt + 1 < NKT_) produceA(kt + 1);  // into slot (kt+1)&1 (read at kt-1)
        }
        __builtin_amdgcn_sched_barrier(0);
    }

    // epilogue: consumers write real rows (C/D map col=lane&15, row=(lane>>4)*4+reg)
    if (w < 6) {
        int ncol[8]; float bs[8];
        #pragma unroll
        for (int g = 0; g < 8; ++g) {
            ncol[g] = w * 128 + g * 16 + (lane & 15);
            bs[g] = bias[ncol[g]];
        }
        #pragma unroll
        for (int f = 0; f < 4; ++f) {
            int rbase = m0 + f * 16 + ((lane >> 4) << 2);
            #pragma unroll
            for (int q = 0; q < 4; ++q) {
                int mc = rbase + q;
                int av = act[mc];
                int gr = mc + ((mc >> 11) << 11);  // b*4096 + c
                size_t orow = (size_t)gr * D_;
                #pragma unroll
                for (int g = 0; g < 8; ++g) {
                    float v = av ? tanh_fast(acc[f][g][q] + bs[g]) : 0.f;
                    out[orow + ncol[g]] = v;
                }
            }
        }
    }

    // all threads: zero this block's 196.6 KB share of the dead region
    {
        int sp = wg >> 5;
        size_t zb = (size_t)(sp * 4096 + 2048) * 3072 + (size_t)(wg & 31) * 196608;
        float4* pz = (float4*)((char*)out + zb);
        float4 zz = make_float4(0.f, 0.f, 0.f, 0.f);
        #pragma unroll
        for (int i = 0; i < 24; ++i) pz[t + i * 512] = zz;
    }
}

extern "C" void kernel_launch(void* const* d_in, const int* in_sizes, int n_in,
                              void* d_out, int out_size, void* d_ws, size_t ws_size,
                              hipStream_t stream) {
    const float* x    = (const float*)d_in[0];
    const int*   seg  = (const int*)d_in[1];
    const int*   padm = (const int*)d_in[2];
    const int*   regm = (const int*)d_in[3];
    const int*   spm  = (const int*)d_in[4];
    const float* Wm   = (const float*)d_in[5];
    const float* bias = (const float*)d_in[6];
    float* out = (float*)d_out;

    char* ws = (char*)d_ws;
    float2* partials = (float2*)ws;               // [128]
    int* stA  = (int*)(ws + 1024);                // [MC_] (b*2048+c)
    int* cntA = stA + MC_;
    int* act  = cntA + MC_;                       // [MC_]
    u16* wt   = (u16*)(act + MC_);                // 768*768 u16, 16B-aligned

    float* out_mp = out + (size_t)M_ * D_;
    float* out_mr = out_mp + M_;
    float* out_sp = out_mr + M_;
    float* out_rate = out_sp + M_;

    prep_kernel<<<META_BLOCKS + WPREP_BLOCKS, 256, 0, stream>>>(
        seg, padm, regm, spm, Wm, wt, stA, cntA, act,
        out_mp, out_mr, out_sp, partials);
    fused_kernel<<<GEMM_BLOCKS + 1, 512, 0, stream>>>(
        x, stA, cntA, wt, bias, act, partials, out, out_rate);
}

// Round 10
// 78.803 us; speedup vs baseline: 1.1341x; 1.1341x over previous
//
#include <hip/hip_runtime.h>
#include <math.h>

#define B_   8
#define L_   4096
#define D_   768
#define NC_  4096
#define NCH_ 2048
#define M_   (B_*NC_)    // 32768 (b,c) pairs
#define MC_  (B_*NCH_)   // 16384 active compact rows
#define NKT_ 24          // K-tiles of 32 (K=768)
#define MB_META 171      // 171*192 >= 32768
#define WPREP_BLOCKS 144
#define MEAN0 (MB_META + WPREP_BLOCKS)
#define ZERO0 (MEAN0 + MC_)
#define GRID1 (ZERO0 + 512)
#define GEMM_BLOCKS 256  // 256 mtiles (BM=64) x 1 ntile (BN=768), 1/CU

typedef __attribute__((ext_vector_type(8))) short short8;
typedef __attribute__((ext_vector_type(4))) float f32x4;
typedef unsigned int u32;
typedef unsigned short u16;

__device__ __forceinline__ void gload16(const void* g, void* l) {
    __builtin_amdgcn_global_load_lds((const __attribute__((address_space(1))) u32*)g,
                                     (__attribute__((address_space(3))) u32*)l, 16, 0, 0);
}

__device__ __forceinline__ u16 f2bf(float f) {           // RNE bf16
    union { float f; u32 u; } v; v.f = f;
    u32 r = v.u + 0x7fffu + ((v.u >> 16) & 1u);
    return (u16)(r >> 16);
}

// tanh(x) = 1 - 2/(e^{2x}+1). Saturates to +-1.
__device__ __forceinline__ float tanh_fast(float x) {
    float e = __builtin_amdgcn_exp2f(x * 2.885390081777927f);
    return 1.f - 2.f * __builtin_amdgcn_rcpf(e + 1.f);
}

// A-plane (bf16 of mean) lives in d_out's dead rows (c>=2048), spans 0..3.
__device__ __forceinline__ size_t aplane_byte(int mc) {
    int span = mc >> 12;
    int rem  = mc & 4095;
    return (size_t)(span * 4096 + 2048) * 3072 + (size_t)rem * 1536;
}

__device__ __forceinline__ int lower_bound(const int* __restrict__ a, int lo, int hi, int v) {
    while (lo < hi) {
        int mid = (lo + hi) >> 1;
        if (a[mid] < v) lo = mid + 1; else hi = mid;
    }
    return lo;
}

// -------- kernel 1: mega = meta + wprep + mean + zero(spans 4-7) --------
// 192 threads/block. Roles by blockIdx:
//  [0,171)      meta: masks, act, num/den partials (idx = c*8+b, shfl tricks)
//  [171,315)    wprep: W[k][n] -> wt[n][k] bf16 (LDS transpose)
//  [315,16699)  mean: self-searched chunk mean -> bf16 A-plane slice
//  [16699,17211) zero: spans 4..7 of dead region (25.2 MB)
__global__ void mega_kernel(const int* __restrict__ seg,
                            const int* __restrict__ padm,
                            const int* __restrict__ regm,
                            const int* __restrict__ spm,
                            const float* __restrict__ Wm,
                            const float* __restrict__ x,
                            u16* __restrict__ wt, int* __restrict__ act,
                            float* __restrict__ out_mp, float* __restrict__ out_mr,
                            float* __restrict__ out_sp,
                            float2* __restrict__ partials,
                            char* __restrict__ outb) {
    __shared__ float shm[64 * 65];
    int blk = blockIdx.x;
    int t = threadIdx.x;                         // 0..191
    if (blk >= MEAN0) {
        int mb = blk - MEAN0;
        if (mb < MC_) {                          // ---- mean role ----
            int b = mb >> 11, c = mb & (NCH_ - 1);
            const int* row = seg + b * L_;
            int s = lower_bound(row, 0, L_, c);      // uniform -> broadcast loads
            int e = lower_bound(row, s, L_, c + 1);
            int cnt = e - s;
            float ax = 0.f, ay = 0.f, az = 0.f, aw = 0.f;
            if (cnt > 0) {
                const float4* base = (const float4*)(x + ((size_t)b * L_ + s) * D_) + t;
                for (int tk = 0; tk < cnt; ++tk) {
                    float4 v = base[tk * 192];
                    ax += v.x; ay += v.y; az += v.z; aw += v.w;
                }
                float inv = 1.f / (float)cnt;
                ax *= inv; ay *= inv; az *= inv; aw *= inv;
            }
            u16* hi = (u16*)(outb + aplane_byte(mb));
            ushort4 h;
            h.x = f2bf(ax); h.y = f2bf(ay); h.z = f2bf(az); h.w = f2bf(aw);
            *(ushort4*)(hi + 4 * t) = h;
            return;
        }
        // ---- zero role: spans 4..7 ----
        int z = mb - MC_;                        // 0..511
        int sp = z >> 7;
        size_t base = (size_t)((4 + sp) * 4096 + 2048) * 3072 + (size_t)(z & 127) * 49152;
        float4* p = (float4*)(outb + base);
        float4 zz = make_float4(0.f, 0.f, 0.f, 0.f);
        #pragma unroll
        for (int i = 0; i < 16; ++i) p[t + i * 192] = zz;
        return;
    }
    if (blk >= MB_META) {                        // ---- wprep role ----
        int wb = blk - MB_META;
        int bk = wb % 12, bn = wb / 12;
        int k0 = bk * 64, n0 = bn * 64;
        for (int i = t; i < 4096; i += 192) {
            int kl = i >> 6, ln = i & 63;
            shm[kl * 65 + ln] = Wm[(size_t)(k0 + kl) * D_ + n0 + ln];  // coalesced over n
        }
        __syncthreads();
        for (int i = t; i < 4096; i += 192) {
            int nl = i >> 6, ln = i & 63;
            wt[(size_t)(n0 + nl) * D_ + k0 + ln] = f2bf(shm[ln * 65 + nl]);
        }
        return;
    }
    // ---- meta role ----
    int idx = blk * 192 + t;                     // may exceed M_ (guarded stores)
    int c = idx >> 3, b = idx & 7;
    const int* row = seg + b * L_;
    int s = lower_bound(row, 0, L_, c);
    int e = __shfl_down(s, 8);                   // lane+8 holds (c+1, b)
    if ((t & 63) >= 56) e = lower_bound(row, s, L_, c + 1);
    int k = 0;
    {
        int mpx = 0;
        if (idx < M_ && e - s > 0) mpx = padm[b * L_ + s];
        k = mpx;                                 // keep = OR over the 8 b's (aligned groups)
        k |= __shfl_xor(k, 1);
        k |= __shfl_xor(k, 2);
        k |= __shfl_xor(k, 4);
        k = k ? 1 : 0;
    }
    float numP = 0.f, denP = 0.f;
    if (idx < M_) {
        int cnt = e - s;
        int mp = 0, mr = 0;
        if (cnt > 0) { mp = padm[b * L_ + s]; mr = regm[b * L_ + s]; }
        int sp = (mp == 0) ? -1 : spm[b * L_ + s];
        out_mp[b * NC_ + c] = (float)mp;         // mp*keep == mp
        out_mr[b * NC_ + c] = (float)(k ? mr : 0);
        out_sp[b * NC_ + c] = (float)(k ? sp : 0);
        if (c < NCH_) act[b * NCH_ + c] = (k && cnt > 0) ? 1 : 0;
        numP = (float)(k ? mr : 0);
        denP = (float)(cnt * mr);
    }
    #pragma unroll
    for (int off = 32; off; off >>= 1) {
        numP += __shfl_down(numP, off);
        denP += __shfl_down(denP, off);
    }
    if ((t & 63) == 0) { shm[(t >> 6) * 2] = numP; shm[(t >> 6) * 2 + 1] = denP; }
    __syncthreads();
    if (t == 0)
        partials[blk] = make_float2(shm[0] + shm[2] + shm[4],
                                    shm[1] + shm[3] + shm[5]);
}

// -------- kernel 2: 64x768 deep-pipelined MFMA GEMM + self-zero (+rate) ----
// Block = sole reader of its 96KB A region -> zeroes it in epilogue.
// 3-buffer ring (A 3x4KB + B 3x48KB), staging 2 K-tiles ahead, 7 gloads per
// wave per K-tile (A duplicated across wave halves), counted vmcnt(7),
// one s_barrier per K-tile, 2 phases x 12 MFMA + setprio.
__global__ __launch_bounds__(512, 1) void gemm8_kernel(
        const char* __restrict__ aBytes,          // d_out bytes (A plane)
        const u16* __restrict__ wt,               // [768][768] transposed bf16
        const float* __restrict__ bias,
        const int* __restrict__ act,
        const float2* __restrict__ partials,
        float* __restrict__ out, float* __restrict__ rateOut) {
    __shared__ char sAB[159744];                  // A ring 0..12287, B ring 12288..
    __shared__ float rb2[16];
    int bid = blockIdx.x;
    int t = threadIdx.x;
    if (bid >= GEMM_BLOCKS) {                     // ---- rate role ----
        float n = 0.f, d = 0.f;
        if (t < MB_META) { float2 p = partials[t]; n = p.x; d = p.y; }
        #pragma unroll
        for (int off = 32; off; off >>= 1) { n += __shfl_down(n, off); d += __shfl_down(d, off); }
        if ((t & 63) == 0) { rb2[t >> 6] = n; rb2[8 + (t >> 6)] = d; }
        __syncthreads();
        if (t == 0) {
            float ns = 0.f, ds = 0.f;
            #pragma unroll
            for (int i = 0; i < 8; ++i) { ns += rb2[i]; ds += rb2[8 + i]; }
            rateOut[0] = ns / ds;
        }
        return;
    }
    char* sA = sAB;
    char* sB = sAB + 12288;
    int wg = (bid & 7) * 32 + (bid >> 3);         // XCD-chunked (256 = 8*32)
    int m0 = wg << 6;
    int lane = t & 63, w = t >> 6;

    const char* aT = aBytes + aplane_byte(m0);    // 64 rows x 1536 B
    const char* bT = (const char*)wt;             // 768 rows x 1536 B

    // A staging src (wave halves duplicate: ta in [0,256))
    int ta = t & 255;
    int rA = ta >> 2, sa = ta & 3;
    int srcA = rA * 1536 + ((sa ^ ((rA ^ (rA >> 2)) & 3)) << 4);
    int dbA = (w & 3) * 1024;
    // B staging src: call j covers rows via i = t + j*512
    int srcB[6];
    #pragma unroll
    for (int j = 0; j < 6; ++j) {
        int i = t + j * 512;
        int r = i >> 2, s = i & 3;
        srcB[j] = r * 1536 + ((s ^ ((r ^ (r >> 2)) & 3)) << 4);
    }
    int dbB = w * 1024;

    // fragment read offsets (swizzled, loop-invariant)
    int aoff[4], boff[6];
    #pragma unroll
    for (int f = 0; f < 4; ++f) {
        int r = f * 16 + (lane & 15);
        aoff[f] = r * 64 + ((((lane >> 4)) ^ ((r ^ (r >> 2)) & 3)) << 4);
    }
    #pragma unroll
    for (int g = 0; g < 6; ++g) {
        int r = w * 96 + g * 16 + (lane & 15);
        boff[g] = r * 64 + ((((lane >> 4)) ^ ((r ^ (r >> 2)) & 3)) << 4);
    }

    f32x4 acc[4][6] = {};

    // prologue: stage K-tiles 0,1 (order per tile: A, B0..B5)
    #pragma unroll
    for (int p = 0; p < 2; ++p) {
        int kof = p << 6;
        gload16(aT + srcA + kof, sA + p * 4096 + dbA);
        #pragma unroll
        for (int j = 0; j < 6; ++j)
            gload16(bT + srcB[j] + kof, sB + p * 49152 + j * 8192 + dbB);
    }

    int cur = 0;
    #pragma unroll 1
    for (int kt = 0; kt < NKT_; ++kt) {
        // tile kt's 7 loads oldest; <=7 newer (tile kt+1) stay in flight
        if (kt < NKT_ - 1) asm volatile("s_waitcnt vmcnt(7)" ::: "memory");
        else               asm volatile("s_waitcnt vmcnt(0)" ::: "memory");
        __builtin_amdgcn_s_barrier();
        __builtin_amdgcn_sched_barrier(0);
        const char* curA = sA + cur * 4096;
        const char* curB = sB + cur * 49152;
        int nxt = cur + 2; if (nxt >= 3) nxt -= 3;
        int kof = (kt + 2) << 6;
        bool st = (kt + 2 < NKT_);
        // ---- phase A: A-frags + B-frags g0-2; stage A,B0,B1,B2; 12 MFMA ----
        short8 afr[4], bfr[3];
        #pragma unroll
        for (int f = 0; f < 4; ++f) afr[f] = *(const short8*)(curA + aoff[f]);
        #pragma unroll
        for (int g = 0; g < 3; ++g) bfr[g] = *(const short8*)(curB + boff[g]);
        if (st) {
            gload16(aT + srcA + kof, sA + nxt * 4096 + dbA);
            gload16(bT + srcB[0] + kof, sB + nxt * 49152 + dbB);
            gload16(bT + srcB[1] + kof, sB + nxt * 49152 + 8192 + dbB);
            gload16(bT + srcB[2] + kof, sB + nxt * 49152 + 16384 + dbB);
        }
        __builtin_amdgcn_s_setprio(1);
        #pragma unroll
        for (int f = 0; f < 4; ++f)
            #pragma unroll
            for (int g = 0; g < 3; ++g)
                acc[f][g] = __builtin_amdgcn_mfma_f32_16x16x32_bf16(
                    afr[f], bfr[g], acc[f][g], 0, 0, 0);
        __builtin_amdgcn_s_setprio(0);
        // ---- phase B: B-frags g3-5; stage B3,B4,B5; 12 MFMA ----
        short8 bfr2[3];
        #pragma unroll
        for (int g = 0; g < 3; ++g) bfr2[g] = *(const short8*)(curB + boff[g + 3]);
        if (st) {
            gload16(bT + srcB[3] + kof, sB + nxt * 49152 + 24576 + dbB);
            gload16(bT + srcB[4] + kof, sB + nxt * 49152 + 32768 + dbB);
            gload16(bT + srcB[5] + kof, sB + nxt * 49152 + 40960 + dbB);
        }
        __builtin_amdgcn_s_setprio(1);
        #pragma unroll
        for (int f = 0; f < 4; ++f)
            #pragma unroll
            for (int g = 0; g < 3; ++g)
                acc[f][g + 3] = __builtin_amdgcn_mfma_f32_16x16x32_bf16(
                    afr[f], bfr2[g], acc[f][g + 3], 0, 0, 0);
        __builtin_amdgcn_s_setprio(0);
        __builtin_amdgcn_sched_barrier(0);
        if (++cur == 3) cur = 0;
    }

    // epilogue: C/D lane map col=lane&15, row=(lane>>4)*4+reg
    int ncol[6]; float bs[6];
    #pragma unroll
    for (int g = 0; g < 6; ++g) {
        ncol[g] = w * 96 + g * 16 + (lane & 15);
        bs[g] = bias[ncol[g]];
    }
    #pragma unroll
    for (int f = 0; f < 4; ++f) {
        int rbase = m0 + f * 16 + ((lane >> 4) << 2);
        #pragma unroll
        for (int q = 0; q < 4; ++q) {
            int mc = rbase + q;
            int av = act[mc];
            int gr = mc + ((mc >> 11) << 11);      // b*4096 + c
            size_t orow = (size_t)gr * D_;
            #pragma unroll
            for (int g = 0; g < 6; ++g) {
                float v = av ? tanh_fast(acc[f][g][q] + bs[g]) : 0.f;
                out[orow + ncol[g]] = v;
            }
        }
    }

    // self-zero: this block is the sole reader of its A region (96 KB)
    float4* pz = (float4*)((char*)out + aplane_byte(m0));
    float4 zz = make_float4(0.f, 0.f, 0.f, 0.f);
    #pragma unroll
    for (int i = 0; i < 12; ++i) pz[t + i * 512] = zz;
}

extern "C" void kernel_launch(void* const* d_in, const int* in_sizes, int n_in,
                              void* d_out, int out_size, void* d_ws, size_t ws_size,
                              hipStream_t stream) {
    const float* x    = (const float*)d_in[0];
    const int*   seg  = (const int*)d_in[1];
    const int*   padm = (const int*)d_in[2];
    const int*   regm = (const int*)d_in[3];
    const int*   spm  = (const int*)d_in[4];
    const float* Wm   = (const float*)d_in[5];
    const float* bias = (const float*)d_in[6];
    float* out = (float*)d_out;

    char* ws = (char*)d_ws;
    float2* partials = (float2*)ws;               // [171]
    int* act  = (int*)(ws + 2048);                // [MC_] (b*2048+c)
    u16* wt   = (u16*)(ws + 2048 + MC_ * 4);      // 768*768 u16, 16B-aligned

    float* out_mp = out + (size_t)M_ * D_;
    float* out_mr = out_mp + M_;
    float* out_sp = out_mr + M_;
    float* out_rate = out_sp + M_;

    mega_kernel<<<GRID1, 192, 0, stream>>>(
        seg, padm, regm, spm, Wm, x, wt, act,
        out_mp, out_mr, out_sp, partials, (char*)d_out);
    gemm8_kernel<<<GEMM_BLOCKS + 1, 512, 0, stream>>>(
        (const char*)d_out, wt, bias, act, partials, out, out_rate);
}